// Round 3
// baseline (293.455 us; speedup 1.0000x reference)
//
#include <hip/hip_runtime.h>
#include <hip/hip_bf16.h>

#define NE   64
#define HDIM 4096
#define NTOK 16384
#define KC   32          // k per LDS tile
#define TOKB 128         // tokens per block
#define LDS_T 130        // padded token stride (floats): bank = (2k + t) % 32

// ---------------------------------------------------------------------------
// Transpose W [E][H] -> Wt [H][E] (enables wave-uniform s_load in the GEMM).
// ---------------------------------------------------------------------------
__global__ __launch_bounds__(256) void transpose_w(
    const float* __restrict__ W, float* __restrict__ Wt) {
    const int e = blockIdx.x;
    for (int k = threadIdx.x; k < HDIM; k += 256)
        Wt[(size_t)k * NE + e] = W[(size_t)e * HDIM + k];
}

// ---------------------------------------------------------------------------
// GEMM: block = 4 waves, tile = 128 tokens x 64 experts x KC k.
// Wave owns 16 experts (uniform s_load_dwordx16 of Wt row -> SGPRs).
// Lane owns 2 adjacent tokens (ds_read_b64 from padded LDS tile).
// x staged global->LDS coalesced, double-buffered, 1 barrier/tile.
// Partial 0 -> out logits region; partials 1.. -> ws.
// ---------------------------------------------------------------------------
template <int KSPLIT>
__global__ __launch_bounds__(256, 4) void gemm_logits(
    const float* __restrict__ x, const float* __restrict__ wt,
    float* __restrict__ part0, float* __restrict__ wspart) {
    constexpr int KPER = HDIM / KSPLIT;
    constexpr int NT   = KPER / KC;
    __shared__ float xst[2 * KC * LDS_T];   // 2 x 16.6 KB

    const int tid  = threadIdx.x;
    const int lane = tid & 63;
    const int wid  = __builtin_amdgcn_readfirstlane(tid >> 6);
    const int e0   = wid * 16;
    const int t0   = blockIdx.x * TOKB;
    const int kbase = blockIdx.y * KPER;

    const int sq = tid & 7;        // staging k-quad 0..7 (KC/4)
    const int st = tid >> 3;       // staging token slot 0..31 (4 passes)

    float acc[2][16];
#pragma unroll
    for (int m = 0; m < 2; ++m)
#pragma unroll
        for (int i = 0; i < 16; ++i) acc[m][i] = 0.f;

    const float* xbase = x + (size_t)t0 * HDIM + kbase + sq * 4;
    float4 r[4];

    auto LOADT = [&](int tl) {
#pragma unroll
        for (int pp = 0; pp < 4; ++pp)
            r[pp] = *reinterpret_cast<const float4*>(
                xbase + (size_t)(st + 32 * pp) * HDIM + tl * KC);
    };
    auto WRITET = [&](int b) {
        float* d = xst + b * (KC * LDS_T);
#pragma unroll
        for (int pp = 0; pp < 4; ++pp) {
            const int t = st + 32 * pp;
            d[(sq * 4 + 0) * LDS_T + t] = r[pp].x;
            d[(sq * 4 + 1) * LDS_T + t] = r[pp].y;
            d[(sq * 4 + 2) * LDS_T + t] = r[pp].z;
            d[(sq * 4 + 3) * LDS_T + t] = r[pp].w;
        }
    };

    LOADT(0);
    WRITET(0);
    const float* wchunk = wt + (size_t)kbase * NE + e0;

    for (int tl = 0; tl < NT; ++tl) {
        if (tl + 1 < NT) LOADT(tl + 1);       // global->reg early (latency hidden)
        __syncthreads();                       // buf[tl&1] ready; prev compute done
        const float* xbuf = xst + (tl & 1) * (KC * LDS_T) + 2 * lane;
        const float* wrow = wchunk + (size_t)tl * KC * NE;
#pragma unroll
        for (int kk = 0; kk < KC; ++kk) {
            const float2 xv = *reinterpret_cast<const float2*>(xbuf + kk * LDS_T);
            float wv[16];
#pragma unroll
            for (int i = 0; i < 16; ++i) wv[i] = wrow[kk * NE + i];  // uniform -> s_load
#pragma unroll
            for (int i = 0; i < 16; ++i) {
                acc[0][i] = fmaf(xv.x, wv[i], acc[0][i]);
                acc[1][i] = fmaf(xv.y, wv[i], acc[1][i]);
            }
        }
        if (tl + 1 < NT) WRITET((tl + 1) & 1); // other buffer; safe post-barrier
    }

    float* dst = (blockIdx.y == 0 ? part0
                                  : wspart + (size_t)(blockIdx.y - 1) * NTOK * NE);
#pragma unroll
    for (int m = 0; m < 2; ++m) {
        float* dr = dst + (size_t)(t0 + 2 * lane + m) * NE + e0;
#pragma unroll
        for (int i4 = 0; i4 < 4; ++i4)
            *reinterpret_cast<float4*>(dr + 4 * i4) =
                make_float4(acc[m][4 * i4 + 0], acc[m][4 * i4 + 1],
                            acc[m][4 * i4 + 2], acc[m][4 * i4 + 3]);
    }
}

// ---------------------------------------------------------------------------
// Router: thread-per-token. Partial 0 lives in the out-logits region; add
// ws partials, write final logits back, softmax*mask -> scores, top-2,
// 2-way softmax + L1 renorm, indices as floats.
// Out layout: [scores 16384*64][logits 16384*64][weights 16384*2][indices 16384*2]
// ---------------------------------------------------------------------------
__global__ __launch_bounds__(256) void router_kernel(
    const float* __restrict__ wspart, const float* __restrict__ mask,
    float* __restrict__ out, int ksplit) {
    const int t = blockIdx.x * 256 + threadIdx.x;
    if (t >= NTOK) return;

    float l[NE];
    float* lo = out + (size_t)NTOK * NE + (size_t)t * NE;  // logits row (= partial 0)
#pragma unroll
    for (int e4 = 0; e4 < NE / 4; ++e4) {
        const float4 v = *reinterpret_cast<const float4*>(&lo[e4 * 4]);
        l[e4 * 4 + 0] = v.x; l[e4 * 4 + 1] = v.y;
        l[e4 * 4 + 2] = v.z; l[e4 * 4 + 3] = v.w;
    }
    for (int c = 1; c < ksplit; ++c) {
        const float* p = wspart + ((size_t)(c - 1) * NTOK + t) * NE;
#pragma unroll
        for (int e4 = 0; e4 < NE / 4; ++e4) {
            const float4 v = *reinterpret_cast<const float4*>(&p[e4 * 4]);
            l[e4 * 4 + 0] += v.x; l[e4 * 4 + 1] += v.y;
            l[e4 * 4 + 2] += v.z; l[e4 * 4 + 3] += v.w;
        }
    }

#pragma unroll
    for (int e4 = 0; e4 < NE / 4; ++e4) {
        const float4 v = make_float4(l[e4 * 4 + 0], l[e4 * 4 + 1],
                                     l[e4 * 4 + 2], l[e4 * 4 + 3]);
        *reinterpret_cast<float4*>(&lo[e4 * 4]) = v;
    }

    float mx = l[0];
#pragma unroll
    for (int e = 1; e < NE; ++e) mx = fmaxf(mx, l[e]);
    float sc[NE];
    float s = 0.f;
#pragma unroll
    for (int e = 0; e < NE; ++e) {
        const float ev = expf(l[e] - mx);
        sc[e] = ev;
        s += ev;
    }
    const float inv = 1.f / s;
    const float* mrow = mask + (size_t)(t >> 12) * NE;
#pragma unroll
    for (int e = 0; e < NE; ++e) sc[e] = mrow[e] * (sc[e] * inv);

    float* so = out + (size_t)t * NE;
#pragma unroll
    for (int e4 = 0; e4 < NE / 4; ++e4) {
        const float4 v = make_float4(sc[e4 * 4 + 0], sc[e4 * 4 + 1],
                                     sc[e4 * 4 + 2], sc[e4 * 4 + 3]);
        *reinterpret_cast<float4*>(&so[e4 * 4]) = v;
    }

    // top-2 (strict > keeps lowest index on ties, matching jax.lax.top_k)
    float v1 = -3.4e38f, v2 = -3.4e38f;
    int i1 = 0, i2 = 0;
#pragma unroll
    for (int e = 0; e < NE; ++e) {
        const float v = sc[e];
        if (v > v1) {
            v2 = v1; i2 = i1;
            v1 = v;  i1 = e;
        } else if (v > v2) {
            v2 = v; i2 = e;
        }
    }

    const float e2v = expf(v2 - v1);
    float w1 = 1.f / (1.f + e2v);
    float w2 = e2v / (1.f + e2v);
    const float sw = w1 + w2;
    w1 /= sw; w2 /= sw;

    const size_t wo = (size_t)2 * NTOK * NE;
    out[wo + (size_t)t * 2 + 0] = w1;
    out[wo + (size_t)t * 2 + 1] = w2;
    const size_t io = wo + (size_t)NTOK * 2;
    out[io + (size_t)t * 2 + 0] = (float)i1;
    out[io + (size_t)t * 2 + 1] = (float)i2;
}

extern "C" void kernel_launch(void* const* d_in, const int* in_sizes, int n_in,
                              void* d_out, int out_size, void* d_ws, size_t ws_size,
                              hipStream_t stream) {
    const float* x    = (const float*)d_in[0];
    const float* mask = (const float*)d_in[1];
    const float* W    = (const float*)d_in[2];
    float* out = (float*)d_out;
    float* ws  = (float*)d_ws;

    const size_t per = (size_t)NTOK * NE * sizeof(float);      // 4 MB per partial
    const size_t wt_bytes = (size_t)HDIM * NE * sizeof(float); // 1 MB

    int ksplit;
    if (ws_size >= 7 * per + wt_bytes)      ksplit = 8;   // 29 MB
    else if (ws_size >= 3 * per + wt_bytes) ksplit = 4;   // 13 MB
    else                                    ksplit = 2;   // 5 MB

    float* wspart = ws;                                    // ksplit-1 partials
    float* wtp    = ws + (size_t)(ksplit - 1) * NTOK * NE; // transposed W
    float* part0  = out + (size_t)NTOK * NE;               // logits region

    transpose_w<<<dim3(NE), dim3(256), 0, stream>>>(W, wtp);

    switch (ksplit) {
        case 8: gemm_logits<8><<<dim3(NTOK / TOKB, 8), dim3(256), 0, stream>>>(x, wtp, part0, wspart); break;
        case 4: gemm_logits<4><<<dim3(NTOK / TOKB, 4), dim3(256), 0, stream>>>(x, wtp, part0, wspart); break;
        default: gemm_logits<2><<<dim3(NTOK / TOKB, 2), dim3(256), 0, stream>>>(x, wtp, part0, wspart); break;
    }

    router_kernel<<<dim3(NTOK / 256), dim3(256), 0, stream>>>(wspart, mask, out, ksplit);
}

// Round 4
// 118.490 us; speedup vs baseline: 2.4766x; 2.4766x over previous
//
#include <hip/hip_runtime.h>
#include <hip/hip_bf16.h>

#define NE     64
#define HDIM   4096
#define NTOK   16384
#define KSPLIT 4
#define KPER   (HDIM / KSPLIT)   // 1024
#define SPW    (KPER / 32)       // 32 k-steps (chunks of 32) per wave
#define NCHUNK (HDIM / 32)       // 128 global k-chunks

typedef __attribute__((ext_vector_type(8))) short bf16x8;   // 8 bf16 = 4 VGPR
typedef __attribute__((ext_vector_type(4))) float f32x4;    // MFMA acc

union FragU { uint4 u; bf16x8 v; };

// round-to-nearest-even f32 -> bf16 (bits), no NaN handling (inputs finite)
__device__ __forceinline__ unsigned rne_bf16(float f) {
    unsigned v = __float_as_uint(f);
    return (v + 0x7FFFu + ((v >> 16) & 1u)) >> 16;
}

// ---------------------------------------------------------------------------
// Pack W [64][4096] fp32 into MFMA B-fragment order, split hi/lo bf16.
// Index: [(chunk*4 + etile)*64 + lane] -> uint4 (8 bf16), elem j of lane l
//   = W[etile*16 + (l&15)][chunk*32 + (l>>4)*8 + j]
// Same k-mapping is used for the A side in the GEMM -> permutation-invariant.
// ---------------------------------------------------------------------------
__global__ __launch_bounds__(256) void prep_w(
    const float* __restrict__ W, uint4* __restrict__ wfh, uint4* __restrict__ wfl) {
    const int idx = blockIdx.x * 256 + threadIdx.x;   // 32768 = 128*4*64
    const int l  = idx & 63;
    const int ce = idx >> 6;
    const int e  = ce & 3;
    const int c  = ce >> 2;
    const float* src = W + (size_t)(e * 16 + (l & 15)) * HDIM + c * 32 + (l >> 4) * 8;

    unsigned hw[4], lw[4];
#pragma unroll
    for (int w = 0; w < 4; ++w) {
        const float x0 = src[2 * w], x1 = src[2 * w + 1];
        const unsigned u0 = __float_as_uint(x0), u1 = __float_as_uint(x1);
        const unsigned h0 = u0 & 0xFFFF0000u, h1 = u1 & 0xFFFF0000u;
        hw[w] = (h0 >> 16) | h1;
        const float l0 = x0 - __uint_as_float(h0);
        const float l1 = x1 - __uint_as_float(h1);
        lw[w] = rne_bf16(l0) | (rne_bf16(l1) << 16);
    }
    wfh[idx] = make_uint4(hw[0], hw[1], hw[2], hw[3]);
    wfl[idx] = make_uint4(lw[0], lw[1], lw[2], lw[3]);
}

// ---------------------------------------------------------------------------
// GEMM via split-bf16 MFMA: logits = x_hi*W_hi + x_lo*W_hi + x_hi*W_lo.
// Block = 4 waves; wave = 16 tokens x 64 experts x KPER k. No LDS/barriers.
// x read direct (fp32, every byte consumed), converted in-register.
// W frags from L2-resident packed buffers (per-lane coalesced 16B loads).
// Partial bk=0 -> out logits region; bk 1..3 -> ws.
// ---------------------------------------------------------------------------
__global__ __launch_bounds__(256) void gemm_logits_mfma(
    const float* __restrict__ x, const uint4* __restrict__ wfh,
    const uint4* __restrict__ wfl, float* __restrict__ part0,
    float* __restrict__ wspart) {
    const int tid  = threadIdx.x;
    const int lane = tid & 63;
    const int wv   = tid >> 6;            // wave 0..3
    const int bt   = blockIdx.x;          // 0..255 token tile
    const int bk   = blockIdx.y;          // 0..3 k-split
    const int t0   = bt * 64 + wv * 16;
    const int ar   = lane & 15;           // A row (token) / D col source
    const int kq   = lane >> 4;           // 0..3 k-quad

    f32x4 acc[4];
#pragma unroll
    for (int e = 0; e < 4; ++e) acc[e] = (f32x4){0.f, 0.f, 0.f, 0.f};

    const float* xr = x + (size_t)(t0 + ar) * HDIM + bk * KPER + kq * 8;
    const int cbase = (bk * SPW) * 4 * 64 + lane;   // frag index base

    float4 xa = *reinterpret_cast<const float4*>(xr);
    float4 xb = *reinterpret_cast<const float4*>(xr + 4);

#pragma unroll 2
    for (int s = 0; s < SPW; ++s) {
        // prefetch next step's x (same addr on last iter; value unused)
        const int sn = (s + 1 < SPW) ? s + 1 : s;
        const float4 nxa = *reinterpret_cast<const float4*>(xr + sn * 32);
        const float4 nxb = *reinterpret_cast<const float4*>(xr + sn * 32 + 4);

        // W fragments for this chunk (hi/lo, 4 expert tiles) — L2 hits
        FragU bh[4], bl[4];
#pragma unroll
        for (int e = 0; e < 4; ++e) {
            const int wi = cbase + (s * 4 + e) * 64;
            bh[e].u = wfh[wi];
            bl[e].u = wfl[wi];
        }

        // split-convert 8 fp32 -> a_hi, a_lo bf16x8
        const unsigned ue[8] = {
            __float_as_uint(xa.x), __float_as_uint(xa.y),
            __float_as_uint(xa.z), __float_as_uint(xa.w),
            __float_as_uint(xb.x), __float_as_uint(xb.y),
            __float_as_uint(xb.z), __float_as_uint(xb.w)};
        FragU ah, al;
#pragma unroll
        for (int w = 0; w < 4; ++w) {
            const unsigned u0 = ue[2 * w], u1 = ue[2 * w + 1];
            const unsigned h0 = u0 & 0xFFFF0000u, h1 = u1 & 0xFFFF0000u;
            ((unsigned*)&ah.u)[w] = (h0 >> 16) | h1;
            const float l0 = __uint_as_float(u0) - __uint_as_float(h0);
            const float l1 = __uint_as_float(u1) - __uint_as_float(h1);
            ((unsigned*)&al.u)[w] = rne_bf16(l0) | (rne_bf16(l1) << 16);
        }

#pragma unroll
        for (int e = 0; e < 4; ++e) {
            acc[e] = __builtin_amdgcn_mfma_f32_16x16x32_bf16(ah.v, bh[e].v, acc[e], 0, 0, 0);
            acc[e] = __builtin_amdgcn_mfma_f32_16x16x32_bf16(al.v, bh[e].v, acc[e], 0, 0, 0);
            acc[e] = __builtin_amdgcn_mfma_f32_16x16x32_bf16(ah.v, bl[e].v, acc[e], 0, 0, 0);
        }
        xa = nxa; xb = nxb;
    }

    // D layout (m89-verified): lane holds D[kq*4 + r][ar] per expert tile
    float* dst = (bk == 0 ? part0 : wspart + (size_t)(bk - 1) * NTOK * NE);
#pragma unroll
    for (int e = 0; e < 4; ++e)
#pragma unroll
        for (int r = 0; r < 4; ++r)
            dst[(size_t)(t0 + kq * 4 + r) * NE + e * 16 + ar] = acc[e][r];
}

// ---------------------------------------------------------------------------
// Router: thread-per-token. Partial 0 lives in the out-logits region; add
// ws partials, write final logits back, softmax*mask -> scores, top-2,
// 2-way softmax + L1 renorm, indices as floats.
// Out layout: [scores 16384*64][logits 16384*64][weights 16384*2][indices 16384*2]
// ---------------------------------------------------------------------------
__global__ __launch_bounds__(256) void router_kernel(
    const float* __restrict__ wspart, const float* __restrict__ mask,
    float* __restrict__ out, int ksplit) {
    const int t = blockIdx.x * 256 + threadIdx.x;
    if (t >= NTOK) return;

    float l[NE];
    float* lo = out + (size_t)NTOK * NE + (size_t)t * NE;  // logits row (= partial 0)
#pragma unroll
    for (int e4 = 0; e4 < NE / 4; ++e4) {
        const float4 v = *reinterpret_cast<const float4*>(&lo[e4 * 4]);
        l[e4 * 4 + 0] = v.x; l[e4 * 4 + 1] = v.y;
        l[e4 * 4 + 2] = v.z; l[e4 * 4 + 3] = v.w;
    }
    for (int c = 1; c < ksplit; ++c) {
        const float* p = wspart + ((size_t)(c - 1) * NTOK + t) * NE;
#pragma unroll
        for (int e4 = 0; e4 < NE / 4; ++e4) {
            const float4 v = *reinterpret_cast<const float4*>(&p[e4 * 4]);
            l[e4 * 4 + 0] += v.x; l[e4 * 4 + 1] += v.y;
            l[e4 * 4 + 2] += v.z; l[e4 * 4 + 3] += v.w;
        }
    }

#pragma unroll
    for (int e4 = 0; e4 < NE / 4; ++e4) {
        const float4 v = make_float4(l[e4 * 4 + 0], l[e4 * 4 + 1],
                                     l[e4 * 4 + 2], l[e4 * 4 + 3]);
        *reinterpret_cast<float4*>(&lo[e4 * 4]) = v;
    }

    float mx = l[0];
#pragma unroll
    for (int e = 1; e < NE; ++e) mx = fmaxf(mx, l[e]);
    float sc[NE];
    float s = 0.f;
#pragma unroll
    for (int e = 0; e < NE; ++e) {
        const float ev = expf(l[e] - mx);
        sc[e] = ev;
        s += ev;
    }
    const float inv = 1.f / s;
    const float* mrow = mask + (size_t)(t >> 12) * NE;
#pragma unroll
    for (int e = 0; e < NE; ++e) sc[e] = mrow[e] * (sc[e] * inv);

    float* so = out + (size_t)t * NE;
#pragma unroll
    for (int e4 = 0; e4 < NE / 4; ++e4) {
        const float4 v = make_float4(sc[e4 * 4 + 0], sc[e4 * 4 + 1],
                                     sc[e4 * 4 + 2], sc[e4 * 4 + 3]);
        *reinterpret_cast<float4*>(&so[e4 * 4]) = v;
    }

    // top-2 (strict > keeps lowest index on ties, matching jax.lax.top_k)
    float v1 = -3.4e38f, v2 = -3.4e38f;
    int i1 = 0, i2 = 0;
#pragma unroll
    for (int e = 0; e < NE; ++e) {
        const float v = sc[e];
        if (v > v1) {
            v2 = v1; i2 = i1;
            v1 = v;  i1 = e;
        } else if (v > v2) {
            v2 = v; i2 = e;
        }
    }

    const float e2v = expf(v2 - v1);
    float w1 = 1.f / (1.f + e2v);
    float w2 = e2v / (1.f + e2v);
    const float sw = w1 + w2;
    w1 /= sw; w2 /= sw;

    const size_t wo = (size_t)2 * NTOK * NE;
    out[wo + (size_t)t * 2 + 0] = w1;
    out[wo + (size_t)t * 2 + 1] = w2;
    const size_t io = wo + (size_t)NTOK * 2;
    out[io + (size_t)t * 2 + 0] = (float)i1;
    out[io + (size_t)t * 2 + 1] = (float)i2;
}

extern "C" void kernel_launch(void* const* d_in, const int* in_sizes, int n_in,
                              void* d_out, int out_size, void* d_ws, size_t ws_size,
                              hipStream_t stream) {
    const float* x    = (const float*)d_in[0];
    const float* mask = (const float*)d_in[1];
    const float* W    = (const float*)d_in[2];
    float* out = (float*)d_out;
    float* ws  = (float*)d_ws;

    // ws layout: 3 fp32 partials (12 MB) + wfh (512 KB) + wfl (512 KB)
    float* wspart = ws;
    uint4* wfh = (uint4*)(ws + (size_t)(KSPLIT - 1) * NTOK * NE);
    uint4* wfl = wfh + (size_t)NCHUNK * 4 * 64;
    float* part0 = out + (size_t)NTOK * NE;   // logits region

    prep_w<<<dim3(NCHUNK * 4 * 64 / 256), dim3(256), 0, stream>>>(W, wfh, wfl);
    gemm_logits_mfma<<<dim3(NTOK / 64, KSPLIT), dim3(256), 0, stream>>>(
        x, wfh, wfl, part0, wspart);
    router_kernel<<<dim3(NTOK / 256), dim3(256), 0, stream>>>(wspart, mask, out, KSPLIT);
}

// Round 5
// 107.192 us; speedup vs baseline: 2.7376x; 1.1054x over previous
//
#include <hip/hip_runtime.h>
#include <hip/hip_bf16.h>

#define NE     64
#define HDIM   4096
#define NTOK   16384
#define KSPLIT 8
#define KPER   (HDIM / KSPLIT)   // 512
#define SPW    (KPER / 32)       // 16 k-steps per wave
#define NCHUNK (HDIM / 32)       // 128 global k-chunks
#define TOKB   128               // tokens per block (4 waves x 32)

typedef __attribute__((ext_vector_type(8))) short bf16x8;   // 8 bf16 = 4 VGPR
typedef __attribute__((ext_vector_type(4))) float f32x4;    // MFMA acc

union FragU { uint4 u; bf16x8 v; };

// round-to-nearest-even f32 -> bf16 (bits), no NaN handling (inputs finite)
__device__ __forceinline__ unsigned rne_bf16(float f) {
    unsigned v = __float_as_uint(f);
    return (v + 0x7FFFu + ((v >> 16) & 1u)) >> 16;
}

// split 8 fp32 -> hi (truncate) + lo (rne of residual); same numerics as R4
__device__ __forceinline__ void split8(const float4 a, const float4 b,
                                       FragU& hi, FragU& lo) {
    const unsigned ue[8] = {
        __float_as_uint(a.x), __float_as_uint(a.y),
        __float_as_uint(a.z), __float_as_uint(a.w),
        __float_as_uint(b.x), __float_as_uint(b.y),
        __float_as_uint(b.z), __float_as_uint(b.w)};
#pragma unroll
    for (int w = 0; w < 4; ++w) {
        const unsigned u0 = ue[2 * w], u1 = ue[2 * w + 1];
        const unsigned h0 = u0 & 0xFFFF0000u, h1 = u1 & 0xFFFF0000u;
        ((unsigned*)&hi.u)[w] = (h0 >> 16) | h1;
        const float l0 = __uint_as_float(u0) - __uint_as_float(h0);
        const float l1 = __uint_as_float(u1) - __uint_as_float(h1);
        ((unsigned*)&lo.u)[w] = rne_bf16(l0) | (rne_bf16(l1) << 16);
    }
}

// ---------------------------------------------------------------------------
// Pack W [64][4096] fp32 into MFMA B-fragment order, split hi/lo bf16.
// elem j of lane l at [(chunk*4+etile)*64+l] = W[etile*16+(l&15)][chunk*32+(l>>4)*8+j]
// ---------------------------------------------------------------------------
__global__ __launch_bounds__(256) void prep_w(
    const float* __restrict__ W, uint4* __restrict__ wfh, uint4* __restrict__ wfl) {
    const int idx = blockIdx.x * 256 + threadIdx.x;   // 32768 = 128*4*64
    const int l  = idx & 63;
    const int ce = idx >> 6;
    const int e  = ce & 3;
    const int c  = ce >> 2;
    const float* src = W + (size_t)(e * 16 + (l & 15)) * HDIM + c * 32 + (l >> 4) * 8;

    unsigned hw[4], lw[4];
#pragma unroll
    for (int w = 0; w < 4; ++w) {
        const float x0 = src[2 * w], x1 = src[2 * w + 1];
        const unsigned u0 = __float_as_uint(x0), u1 = __float_as_uint(x1);
        const unsigned h0 = u0 & 0xFFFF0000u, h1 = u1 & 0xFFFF0000u;
        hw[w] = (h0 >> 16) | h1;
        const float l0 = x0 - __uint_as_float(h0);
        const float l1 = x1 - __uint_as_float(h1);
        lw[w] = rne_bf16(l0) | (rne_bf16(l1) << 16);
    }
    wfh[idx] = make_uint4(hw[0], hw[1], hw[2], hw[3]);
    wfl[idx] = make_uint4(lw[0], lw[1], lw[2], lw[3]);
}

// ---------------------------------------------------------------------------
// GEMM via split-bf16 MFMA: logits = x_hi*W_hi + x_lo*W_hi + x_hi*W_lo.
// Wave = 32 tokens (2 A-frags) x 64 experts x KPER k. No LDS, no barriers.
// x: direct fp32 reads, 2-deep prefetch ring (HBM latency cover).
// W: packed frags from L2 (per-lane 16B loads), shared k-mapping with A side.
// Partial bk=0 -> out logits region; bk 1..7 -> ws.
// ---------------------------------------------------------------------------
__global__ __launch_bounds__(256, 4) void gemm_logits_mfma(
    const float* __restrict__ x, const uint4* __restrict__ wfh,
    const uint4* __restrict__ wfl, float* __restrict__ part0,
    float* __restrict__ wspart) {
    const int tid  = threadIdx.x;
    const int lane = tid & 63;
    const int wv   = tid >> 6;            // wave 0..3
    const int t0   = blockIdx.x * TOKB + wv * 32;
    const int bk   = blockIdx.y;          // 0..7 k-split
    const int ar   = lane & 15;           // A row within frag / D col (expert)
    const int kq   = lane >> 4;           // 0..3 k-quad

    f32x4 acc[2][4];
#pragma unroll
    for (int f = 0; f < 2; ++f)
#pragma unroll
        for (int e = 0; e < 4; ++e) acc[f][e] = (f32x4){0.f, 0.f, 0.f, 0.f};

    const float* xr0 = x + (size_t)(t0 + ar) * HDIM + bk * KPER + kq * 8;
    const float* xr1 = xr0 + (size_t)16 * HDIM;
    const int cbase = (bk * SPW) * 4 * 64 + lane;

    // 2-deep prefetch ring: slot s&1 holds step s's 4 float4
    float4 px[2][4];
#pragma unroll
    for (int p = 0; p < 2; ++p) {
        px[p][0] = *reinterpret_cast<const float4*>(xr0 + p * 32);
        px[p][1] = *reinterpret_cast<const float4*>(xr0 + p * 32 + 4);
        px[p][2] = *reinterpret_cast<const float4*>(xr1 + p * 32);
        px[p][3] = *reinterpret_cast<const float4*>(xr1 + p * 32 + 4);
    }

#pragma unroll 2
    for (int s = 0; s < SPW; ++s) {
        const int slot = s & 1;
        const float4 c0 = px[slot][0], c1 = px[slot][1];
        const float4 c2 = px[slot][2], c3 = px[slot][3];
        if (s + 2 < SPW) {
            px[slot][0] = *reinterpret_cast<const float4*>(xr0 + (s + 2) * 32);
            px[slot][1] = *reinterpret_cast<const float4*>(xr0 + (s + 2) * 32 + 4);
            px[slot][2] = *reinterpret_cast<const float4*>(xr1 + (s + 2) * 32);
            px[slot][3] = *reinterpret_cast<const float4*>(xr1 + (s + 2) * 32 + 4);
        }

        FragU bh[4], bl[4];
#pragma unroll
        for (int e = 0; e < 4; ++e) {
            const int wi = cbase + (s * 4 + e) * 64;
            bh[e].u = wfh[wi];
            bl[e].u = wfl[wi];
        }

        FragU ah0, al0, ah1, al1;
        split8(c0, c1, ah0, al0);
        split8(c2, c3, ah1, al1);

#pragma unroll
        for (int e = 0; e < 4; ++e) {
            acc[0][e] = __builtin_amdgcn_mfma_f32_16x16x32_bf16(ah0.v, bh[e].v, acc[0][e], 0, 0, 0);
            acc[0][e] = __builtin_amdgcn_mfma_f32_16x16x32_bf16(al0.v, bh[e].v, acc[0][e], 0, 0, 0);
            acc[0][e] = __builtin_amdgcn_mfma_f32_16x16x32_bf16(ah0.v, bl[e].v, acc[0][e], 0, 0, 0);
            acc[1][e] = __builtin_amdgcn_mfma_f32_16x16x32_bf16(ah1.v, bh[e].v, acc[1][e], 0, 0, 0);
            acc[1][e] = __builtin_amdgcn_mfma_f32_16x16x32_bf16(al1.v, bh[e].v, acc[1][e], 0, 0, 0);
            acc[1][e] = __builtin_amdgcn_mfma_f32_16x16x32_bf16(ah1.v, bl[e].v, acc[1][e], 0, 0, 0);
        }
    }

    // D layout (m89-verified): lane holds D[f*16 + kq*4 + r][e*16 + ar]
    float* dst = (bk == 0 ? part0 : wspart + (size_t)(bk - 1) * NTOK * NE);
#pragma unroll
    for (int f = 0; f < 2; ++f)
#pragma unroll
        for (int e = 0; e < 4; ++e)
#pragma unroll
            for (int r = 0; r < 4; ++r)
                dst[(size_t)(t0 + f * 16 + kq * 4 + r) * NE + e * 16 + ar] = acc[f][e][r];
}

// ---------------------------------------------------------------------------
// Router: thread-per-token. Partial 0 lives in the out-logits region; add
// ws partials, write final logits back, softmax*mask -> scores, top-2,
// 2-way softmax + L1 renorm, indices as floats.
// Out layout: [scores 16384*64][logits 16384*64][weights 16384*2][indices 16384*2]
// ---------------------------------------------------------------------------
__global__ __launch_bounds__(256) void router_kernel(
    const float* __restrict__ wspart, const float* __restrict__ mask,
    float* __restrict__ out, int ksplit) {
    const int t = blockIdx.x * 256 + threadIdx.x;
    if (t >= NTOK) return;

    float l[NE];
    float* lo = out + (size_t)NTOK * NE + (size_t)t * NE;  // logits row (= partial 0)
#pragma unroll
    for (int e4 = 0; e4 < NE / 4; ++e4) {
        const float4 v = *reinterpret_cast<const float4*>(&lo[e4 * 4]);
        l[e4 * 4 + 0] = v.x; l[e4 * 4 + 1] = v.y;
        l[e4 * 4 + 2] = v.z; l[e4 * 4 + 3] = v.w;
    }
    for (int c = 1; c < ksplit; ++c) {
        const float* p = wspart + ((size_t)(c - 1) * NTOK + t) * NE;
#pragma unroll
        for (int e4 = 0; e4 < NE / 4; ++e4) {
            const float4 v = *reinterpret_cast<const float4*>(&p[e4 * 4]);
            l[e4 * 4 + 0] += v.x; l[e4 * 4 + 1] += v.y;
            l[e4 * 4 + 2] += v.z; l[e4 * 4 + 3] += v.w;
        }
    }

#pragma unroll
    for (int e4 = 0; e4 < NE / 4; ++e4) {
        const float4 v = make_float4(l[e4 * 4 + 0], l[e4 * 4 + 1],
                                     l[e4 * 4 + 2], l[e4 * 4 + 3]);
        *reinterpret_cast<float4*>(&lo[e4 * 4]) = v;
    }

    float mx = l[0];
#pragma unroll
    for (int e = 1; e < NE; ++e) mx = fmaxf(mx, l[e]);
    float sc[NE];
    float s = 0.f;
#pragma unroll
    for (int e = 0; e < NE; ++e) {
        const float ev = expf(l[e] - mx);
        sc[e] = ev;
        s += ev;
    }
    const float inv = 1.f / s;
    const float* mrow = mask + (size_t)(t >> 12) * NE;
#pragma unroll
    for (int e = 0; e < NE; ++e) sc[e] = mrow[e] * (sc[e] * inv);

    float* so = out + (size_t)t * NE;
#pragma unroll
    for (int e4 = 0; e4 < NE / 4; ++e4) {
        const float4 v = make_float4(sc[e4 * 4 + 0], sc[e4 * 4 + 1],
                                     sc[e4 * 4 + 2], sc[e4 * 4 + 3]);
        *reinterpret_cast<float4*>(&so[e4 * 4]) = v;
    }

    // top-2 (strict > keeps lowest index on ties, matching jax.lax.top_k)
    float v1 = -3.4e38f, v2 = -3.4e38f;
    int i1 = 0, i2 = 0;
#pragma unroll
    for (int e = 0; e < NE; ++e) {
        const float v = sc[e];
        if (v > v1) {
            v2 = v1; i2 = i1;
            v1 = v;  i1 = e;
        } else if (v > v2) {
            v2 = v; i2 = e;
        }
    }

    const float e2v = expf(v2 - v1);
    float w1 = 1.f / (1.f + e2v);
    float w2 = e2v / (1.f + e2v);
    const float sw = w1 + w2;
    w1 /= sw; w2 /= sw;

    const size_t wo = (size_t)2 * NTOK * NE;
    out[wo + (size_t)t * 2 + 0] = w1;
    out[wo + (size_t)t * 2 + 1] = w2;
    const size_t io = wo + (size_t)NTOK * 2;
    out[io + (size_t)t * 2 + 0] = (float)i1;
    out[io + (size_t)t * 2 + 1] = (float)i2;
}

extern "C" void kernel_launch(void* const* d_in, const int* in_sizes, int n_in,
                              void* d_out, int out_size, void* d_ws, size_t ws_size,
                              hipStream_t stream) {
    const float* x    = (const float*)d_in[0];
    const float* mask = (const float*)d_in[1];
    const float* W    = (const float*)d_in[2];
    float* out = (float*)d_out;
    float* ws  = (float*)d_ws;

    // ws layout: 7 fp32 partials (28 MB) + wfh (512 KB) + wfl (512 KB)
    float* wspart = ws;
    uint4* wfh = (uint4*)(ws + (size_t)(KSPLIT - 1) * NTOK * NE);
    uint4* wfl = wfh + (size_t)NCHUNK * 4 * 64;
    float* part0 = out + (size_t)NTOK * NE;   // logits region

    prep_w<<<dim3(NCHUNK * 4 * 64 / 256), dim3(256), 0, stream>>>(W, wfh, wfl);
    gemm_logits_mfma<<<dim3(NTOK / TOKB, KSPLIT), dim3(256), 0, stream>>>(
        x, wfh, wfl, part0, wspart);
    router_kernel<<<dim3(NTOK / 256), dim3(256), 0, stream>>>(wspart, mask, out, KSPLIT);
}